// Round 5
// baseline (483.989 us; speedup 1.0000x reference)
//
#include <hip/hip_runtime.h>

// GlobalLinear: per-graph mean of node/edge features, then 3 linear
// projections + bias. DN = DG = DO = 128, DE = 64. Memory-bound:
// nodes 256 MB + edges 256 MB compulsory reads.
// R1-R3: VGPR-return loads and global_load_lds DMA ring all wall ~3.35 TB/s.
// R4 WIN: nontemporal loads (no L3 allocate -> no forced dirty writebacks)
//   agg ~151 -> ~119 us. Remaining gap vs ~6.3 TB/s read ceiling blamed on
//   split-footprint load instructions + sub-group tails.
// R5: flat 64-float4 (1 KB) slot streaming. Each wave owns a CONTIGUOUS run
//   of slots; every load instr covers exactly 1 KB; unroll x4; column phase
//   is lane-invariant because 64 % RF == 0.

#define DN 128
#define DE 64
#define DO 128
#define NCHUNK 8      // blocks per graph per stream -> 8000 blocks total
#define NW 4          // waves per 256-thread block
#define U  4          // unrolled slots in flight per wave

typedef float f4v __attribute__((ext_vector_type(4)));

__device__ __forceinline__ f4v nt_load(const f4v* p) {
    return __builtin_nontemporal_load(p);
}

// ---------------------------------------------------------------------------
// Kernel 1: exclusive prefix-sum of per-graph lengths -> segment offsets.
// ---------------------------------------------------------------------------
__global__ __launch_bounds__(512) void scan_offsets_kernel(
    const int* __restrict__ nlen, const int* __restrict__ elen, int G,
    int* __restrict__ noff, int* __restrict__ eoff)
{
    __shared__ int sn[512], se[512];
    __shared__ int carry_n, carry_e;
    const int t = threadIdx.x;
    if (t == 0) { carry_n = 0; carry_e = 0; }
    __syncthreads();

    for (int base = 0; base < G; base += 512) {
        const int idx = base + t;
        const int vn = (idx < G) ? nlen[idx] : 0;
        const int ve = (idx < G) ? elen[idx] : 0;
        sn[t] = vn; se[t] = ve;
        __syncthreads();
        for (int off = 1; off < 512; off <<= 1) {
            const int an = (t >= off) ? sn[t - off] : 0;
            const int ae = (t >= off) ? se[t - off] : 0;
            __syncthreads();
            sn[t] += an; se[t] += ae;
            __syncthreads();
        }
        if (idx < G) {
            noff[idx] = carry_n + sn[t] - vn;   // exclusive
            eoff[idx] = carry_e + se[t] - ve;
        }
        __syncthreads();
        if (t == 0) {
            const int last = (G - base < 512) ? (G - base - 1) : 511;
            carry_n += sn[last];
            carry_e += se[last];
        }
        __syncthreads();
    }
}

// ---------------------------------------------------------------------------
// Kernel 2: fused node+edge segment-sum, flat 1 KB slot streaming.
// A graph's feature block is a flat array of T = len*RF float4 (RF = f4/row).
// Slot s = f4 range [64s, 64s+64): one wave-wide nt float4 load = 1 KB
// contiguous. Since 64 % RF == 0, lane l always holds column (l & (RF-1)),
// so per-lane f4 accumulators keep a fixed column phase. Chunk -> block,
// wave -> contiguous sub-run of slots, x4 unrolled. LDS tree-reduce over
// replicas, then atomicAdd into the per-graph sum.
// ---------------------------------------------------------------------------
__global__ __launch_bounds__(256) void agg_kernel(
    const float* __restrict__ nodes, const float* __restrict__ edges,
    const int* __restrict__ noff, const int* __restrict__ eoff,
    const int* __restrict__ nlen, const int* __restrict__ elen,
    float* __restrict__ nsum, float* __restrict__ esum, int G)
{
    __shared__ f4v sm[256];
    const int b = blockIdx.x;
    const int t = threadIdx.x;
    const int lane = t & 63;
    const int w = t >> 6;

    const bool is_node = (b < G * NCHUNK);
    const int gb = is_node ? b : (b - G * NCHUNK);
    const int g = gb / NCHUNK;
    const int c = gb % NCHUNK;
    const int RF = is_node ? (DN / 4) : (DE / 4);
    const int len = is_node ? nlen[g] : elen[g];
    const int off = is_node ? noff[g] : eoff[g];
    const f4v* __restrict__ src =
        (const f4v*)(is_node ? nodes : edges) + (size_t)off * RF;
    float* __restrict__ dst =
        is_node ? &nsum[(size_t)g * DN] : &esum[(size_t)g * DE];

    const int T = len * RF;          // total float4 in this graph's block
    const int nslots = T >> 6;       // full 1 KB slots
    const int rem = T & 63;          // trailing float4 (0 when len*RF%64==0)

    // chunk c owns slots [cs, cs+cn)
    const int per_c = nslots / NCHUNK, ex_c = nslots % NCHUNK;
    const int cs = c * per_c + (c < ex_c ? c : ex_c);
    const int cn = per_c + (c < ex_c ? 1 : 0);
    // wave w owns a contiguous sub-run [ws, ws+wn)
    const int per_w = cn / NW, ex_w = cn % NW;
    const int ws = cs + w * per_w + (w < ex_w ? w : ex_w);
    const int wn = per_w + (w < ex_w ? 1 : 0);

    const f4v* __restrict__ p = src + ((size_t)ws << 6) + lane;

    f4v a0 = {0.f, 0.f, 0.f, 0.f}, a1 = a0, a2 = a0, a3 = a0;
    int k = 0;
    for (; k + U <= wn; k += U) {
        const f4v v0 = nt_load(p + ((size_t)(k + 0) << 6));
        const f4v v1 = nt_load(p + ((size_t)(k + 1) << 6));
        const f4v v2 = nt_load(p + ((size_t)(k + 2) << 6));
        const f4v v3 = nt_load(p + ((size_t)(k + 3) << 6));
        a0 += v0; a1 += v1; a2 += v2; a3 += v3;
    }
    for (; k < wn; ++k) {
        a0 += nt_load(p + ((size_t)k << 6));
    }
    const f4v acc = (a0 + a1) + (a2 + a3);

    // graph-level sub-slot tail: handled once, by chunk 0
    if (c == 0 && rem && t < rem) {
        const int f = (nslots << 6) + t;
        const f4v v = nt_load(src + f);
        const int col = f & (RF - 1);
        atomicAdd(&dst[col * 4 + 0], v.x);
        atomicAdd(&dst[col * 4 + 1], v.y);
        atomicAdd(&dst[col * 4 + 2], v.z);
        atomicAdd(&dst[col * 4 + 3], v.w);
    }

    // tree-reduce replicas: thread t holds column phase t & (RF-1)
    sm[t] = acc;
    __syncthreads();
    for (int s = 128; s >= RF; s >>= 1) {
        if (t < s) sm[t] += sm[t + s];
        __syncthreads();
    }
    if (t < RF) {
        const f4v v = sm[t];
        atomicAdd(&dst[t * 4 + 0], v.x);
        atomicAdd(&dst[t * 4 + 1], v.y);
        atomicAdd(&dst[t * 4 + 2], v.z);
        atomicAdd(&dst[t * 4 + 3], v.w);
    }
}

// ---------------------------------------------------------------------------
// Kernel 3: out[g,o] = mean_n(g)·Wn[o] + mean_e(g)·We[o] + glob[g]·Wg[o] + bias[o]
// ---------------------------------------------------------------------------
__global__ __launch_bounds__(128) void finalize_kernel(
    const float* __restrict__ nsum, const float* __restrict__ esum,
    const float* __restrict__ glob,
    const float* __restrict__ Wn, const float* __restrict__ We,
    const float* __restrict__ Wg, const float* __restrict__ bias,
    const int* __restrict__ nlen, const int* __restrict__ elen,
    float* __restrict__ out)
{
    __shared__ float sn[DN], se_[DE], sg[DN];
    const int g = blockIdx.x;
    const int o = threadIdx.x;

    const int nl = nlen[g];
    const int el = elen[g];
    const float inv_n = 1.0f / (float)((nl > 1) ? nl : 1);
    const float inv_e = 1.0f / (float)((el > 1) ? el : 1);

    sn[o] = nsum[(size_t)g * DN + o] * inv_n;
    sg[o] = glob[(size_t)g * DN + o];
    if (o < DE) se_[o] = esum[(size_t)g * DE + o] * inv_e;
    __syncthreads();

    float acc = bias[o];
    const float4* __restrict__ wn = (const float4*)(Wn + (size_t)o * DN);
    const float4* __restrict__ wg = (const float4*)(Wg + (size_t)o * DN);
    const float4* __restrict__ we = (const float4*)(We + (size_t)o * DE);
    const float4* s4n = (const float4*)sn;
    const float4* s4g = (const float4*)sg;
    const float4* s4e = (const float4*)se_;

    #pragma unroll
    for (int i = 0; i < DN / 4; ++i) {
        const float4 a = wn[i], v = s4n[i];
        acc += a.x * v.x + a.y * v.y + a.z * v.z + a.w * v.w;
    }
    #pragma unroll
    for (int i = 0; i < DN / 4; ++i) {
        const float4 a = wg[i], v = s4g[i];
        acc += a.x * v.x + a.y * v.y + a.z * v.z + a.w * v.w;
    }
    #pragma unroll
    for (int i = 0; i < DE / 4; ++i) {
        const float4 a = we[i], v = s4e[i];
        acc += a.x * v.x + a.y * v.y + a.z * v.z + a.w * v.w;
    }
    out[(size_t)g * DO + o] = acc;
}

// ---------------------------------------------------------------------------
extern "C" void kernel_launch(void* const* d_in, const int* in_sizes, int n_in,
                              void* d_out, int out_size, void* d_ws, size_t ws_size,
                              hipStream_t stream)
{
    const float* nodes = (const float*)d_in[0];
    const float* edges = (const float*)d_in[1];
    const float* glob  = (const float*)d_in[2];
    const float* Wn    = (const float*)d_in[3];
    const float* We    = (const float*)d_in[4];
    const float* Wg    = (const float*)d_in[5];
    const float* bias  = (const float*)d_in[6];
    const int*   nlen  = (const int*)d_in[7];
    const int*   elen  = (const int*)d_in[8];
    float*       out   = (float*)d_out;

    const int G = in_sizes[7];           // 500

    // workspace layout: nsum[G*128] | esum[G*64] | noff[G] | eoff[G]
    float* nsum = (float*)d_ws;
    float* esum = nsum + (size_t)G * DN;
    int*   noff = (int*)(esum + (size_t)G * DE);
    int*   eoff = noff + G;

    hipMemsetAsync(d_ws, 0, (size_t)G * (DN + DE) * sizeof(float), stream);

    scan_offsets_kernel<<<1, 512, 0, stream>>>(nlen, elen, G, noff, eoff);

    const int agg_blocks = G * NCHUNK * 2;   // node chunks + edge chunks
    agg_kernel<<<agg_blocks, 256, 0, stream>>>(nodes, edges, noff, eoff,
                                               nlen, elen, nsum, esum, G);

    finalize_kernel<<<G, 128, 0, stream>>>(nsum, esum, glob, Wn, We, Wg, bias,
                                           nlen, elen, out);
}